// Round 6
// baseline (252.367 us; speedup 1.0000x reference)
//
#include <hip/hip_runtime.h>

// PerturbedTopK: x(32,2048) f32, noise(32,500,2048) f32.
// out = [indicators (32,128,2048) f32, idx (32,500,128) as f32], concatenated.
//
// R6: coalesced interleaved ownership in select. Lane owns e = j*256+lane*4+c
// (8 float4 quads, 16B lane stride) so every global_load_dwordx4 is 1KB
// contiguous (full-line consumption; R5's layout touched 64 lines/instr).
// Compaction stays ascending-index via per-j segment ballot scans. Radix
// select w/ common-prefix skip + early exit (R5). Hist from R4.

constexpr int B_     = 32;
constexpr int D_     = 2048;
constexpr int NS_    = 500;
constexpr int TOPK_  = 128;
constexpr float SIGMA_  = 0.05f;
constexpr float MARGIN_ = 0.25f;
constexpr int PER_LANE_ = D_ / 64;       // 32
constexpr int NQ_    = PER_LANE_ / 4;    // 8 quads per lane
constexpr int WAVES_PER_BLOCK_ = 4;
constexpr int CAP_   = 256;              // fast-path candidate cap (4 slots)
constexpr int SLOTS_ = CAP_ / 64;        // 4
constexpr int JCHUNK_ = 8;               // ranks per hist block

__device__ __forceinline__ uint32_t order_key(float f) {
  uint32_t u = __float_as_uint(f);
  return (u & 0x80000000u) ? ~u : (u | 0x80000000u);
}
__device__ __forceinline__ float inv_key(uint32_t k) {
  uint32_t u = (k & 0x80000000u) ? (k & 0x7FFFFFFFu) : ~k;
  return __uint_as_float(u);
}

// ---- kernel 1: per-b float cutoff (exact 128th largest of x_b, minus margin) ----
__global__ __launch_bounds__(64) void ptk_cutoff(const float* __restrict__ x,
                                                 float* __restrict__ cutf) {
  const int lane = threadIdx.x & 63;
  const int b = blockIdx.x;
  const float* __restrict__ xr = x + (size_t)b * D_;
  uint32_t keys[PER_LANE_];
#pragma unroll
  for (int j = 0; j < PER_LANE_; j += 4) {
    const float4 xv = *reinterpret_cast<const float4*>(xr + lane * PER_LANE_ + j);
    keys[j + 0] = order_key(xv.x); keys[j + 1] = order_key(xv.y);
    keys[j + 2] = order_key(xv.z); keys[j + 3] = order_key(xv.w);
  }
  uint32_t prefix = 0; int k = TOPK_;
#pragma unroll 1
  for (int bit = 31; bit >= 0; --bit) {
    const uint32_t want = (prefix >> bit) | 1u;
    int c = 0;
#pragma unroll
    for (int j = 0; j < PER_LANE_; ++j) c += ((keys[j] >> bit) == want) ? 1 : 0;
#pragma unroll
    for (int off = 32; off >= 1; off >>= 1) c += __shfl_xor(c, off);
    if (c >= k) prefix |= (1u << bit); else k -= c;
  }
  if (lane == 0) cutf[b] = inv_key(prefix) - MARGIN_;
}

// ---- kernel 2: selection, writes idx only ----
__global__ __launch_bounds__(256) void ptk_select(
    const float* __restrict__ x, const float* __restrict__ noise,
    const float* __restrict__ cutf, float* __restrict__ out_idx) {
  __shared__ uint2 comp[WAVES_PER_BLOCK_][CAP_];

  const int lane = threadIdx.x & 63;
  const int wave = threadIdx.x >> 6;
  const int row  = blockIdx.x * WAVES_PER_BLOCK_ + wave;   // 0..15999
  const int b = row / NS_;

  const float4* __restrict__ xr4 =
      reinterpret_cast<const float4*>(x + (size_t)b * D_);
  const float4* __restrict__ nr4 =
      reinterpret_cast<const float4*>(noise + (size_t)row * D_);

  // interleaved ownership: element e(j,c) = j*256 + lane*4 + c
  float4 nv[NQ_], xv[NQ_];
#pragma unroll
  for (int j = 0; j < NQ_; ++j) nv[j] = nr4[(j << 6) + lane];
#pragma unroll
  for (int j = 0; j < NQ_; ++j) xv[j] = xr4[(j << 6) + lane];

  float p[PER_LANE_];
#pragma unroll
  for (int j = 0; j < NQ_; ++j) {
    p[4 * j + 0] = fmaf(SIGMA_, nv[j].x, xv[j].x);
    p[4 * j + 1] = fmaf(SIGMA_, nv[j].y, xv[j].y);
    p[4 * j + 2] = fmaf(SIGMA_, nv[j].z, xv[j].z);
    p[4 * j + 3] = fmaf(SIGMA_, nv[j].w, xv[j].w);
  }

  const float cf = cutf[b];   // wave-uniform

  uint32_t m = 0;
#pragma unroll
  for (int t = 0; t < PER_LANE_; ++t) m |= (p[t] >= cf) ? (1u << t) : 0u;

  // per-j segment scans (segments ordered (j, lane) = ascending element index)
  const uint64_t below = (lane == 0) ? 0ull : ((~0ull) >> (64 - lane));
  int pre[NQ_], tot[NQ_];
#pragma unroll
  for (int j = 0; j < NQ_; ++j) {
    const int cnt = __popc((m >> (4 * j)) & 0xFu);     // 0..4
    const uint64_t b0 = __ballot(cnt & 1);
    const uint64_t b1 = __ballot(cnt & 2);
    const uint64_t b2 = __ballot(cnt & 4);
    pre[j] = (int)__popcll(b0 & below) + 2 * (int)__popcll(b1 & below) +
             4 * (int)__popcll(b2 & below);
    tot[j] = (int)__popcll(b0) + 2 * (int)__popcll(b1) + 4 * (int)__popcll(b2);
  }
  int jbase[NQ_]; int C = 0;
#pragma unroll
  for (int j = 0; j < NQ_; ++j) { jbase[j] = C; C += tot[j]; }

  float* __restrict__ idx_row = out_idx + (size_t)row * TOPK_;

  if (C >= TOPK_ && C <= CAP_) {
    // ---------- fast path ----------
#pragma unroll
    for (int j = 0; j < NQ_; ++j) {
      uint32_t nib = (m >> (4 * j)) & 0xFu;
      int q = jbase[j] + pre[j];
      while (nib) {
        const int c = __ffs(nib) - 1; nib &= nib - 1;
        comp[wave][q] = make_uint2(order_key(p[4 * j + c]),
                                   (uint32_t)((j << 8) + (lane << 2) + c));
        ++q;
      }
    }
    __asm__ volatile("s_waitcnt lgkmcnt(0)" ::: "memory");

    uint32_t kk[SLOTS_], ki[SLOTS_];
    bool valid[SLOTS_];
#pragma unroll
    for (int s = 0; s < SLOTS_; ++s) {
      const int q = (s << 6) + lane;
      valid[s] = (q < C);
      const uint2 v = valid[s] ? comp[wave][q] : make_uint2(0u, 0u);
      kk[s] = v.x; ki[s] = v.y;   // pad key 0 never matches a radix class
    }

    // common-prefix skip: and/or reduce over candidate keys
    uint32_t orv = 0u, andv = 0xFFFFFFFFu;
#pragma unroll
    for (int s = 0; s < SLOTS_; ++s) {
      orv  |= valid[s] ? kk[s] : 0u;
      andv &= valid[s] ? kk[s] : 0xFFFFFFFFu;
    }
#pragma unroll
    for (int off = 32; off >= 1; off >>= 1) {
      orv  |= __shfl_xor(orv, off);
      andv &= __shfl_xor(andv, off);
    }
    const uint32_t diff = orv ^ andv;

    uint32_t prefix; int r;
    if (diff == 0u) {
      prefix = orv; r = TOPK_;
    } else {
      const int startbit = 31 - __clz(diff);
      prefix = (startbit == 31) ? 0u : (andv & (0xFFFFFFFFu << (startbit + 1)));
      int k = TOPK_;
      int A = C;
#pragma unroll 1
      for (int bit = startbit; bit >= 0; --bit) {
        const uint32_t want = (prefix >> bit) | 1u;
        int c = 0;
#pragma unroll
        for (int s = 0; s < SLOTS_; ++s)
          c += __popcll(__ballot((kk[s] >> bit) == want));
        if (c >= k) { prefix |= (1u << bit); A = c; }
        else        { k -= c; A -= c; }
        if (A == 1) {
          uint32_t mykey = 0u; bool have = false;
#pragma unroll
          for (int s = 0; s < SLOTS_; ++s) {
            const bool hit = valid[s] && ((kk[s] >> bit) == (prefix >> bit));
            mykey = hit ? kk[s] : mykey;
            have |= hit;
          }
          const uint64_t mb = __ballot(have);
          const int src = __ffsll((unsigned long long)mb) - 1;
          prefix = __shfl(mykey, src);
          k = 1;
          break;
        }
      }
      r = k;
    }

    // ballot-ranked emission, ascending index order
    int sel_run = 0, eq_run = 0;
#pragma unroll
    for (int s = 0; s < SLOTS_; ++s) {
      const bool gt = kk[s] > prefix;
      const bool eq = kk[s] == prefix;
      const uint64_t meq = __ballot(eq);
      const int eqrank = eq_run + __popcll(meq & below);
      const bool sel = gt || (eq && (eqrank < r));
      const uint64_t msel = __ballot(sel);
      if (sel) {
        const int pos = sel_run + __popcll(msel & below);
        idx_row[pos] = (float)(int)ki[s];
      }
      sel_run += __popcll(msel);
      eq_run  += __popcll(meq);
    }
  } else {
    // ---------- fallback (rare): contiguous reload + exact R1 select ----------
    const float* __restrict__ xr = x + (size_t)b * D_;
    const float* __restrict__ nr = noise + (size_t)row * D_;
    const int base_i = lane * PER_LANE_;
    uint32_t keys[PER_LANE_];
#pragma unroll
    for (int j = 0; j < PER_LANE_; ++j)
      keys[j] = order_key(fmaf(SIGMA_, nr[base_i + j], xr[base_i + j]));

    uint32_t prefix = 0; int k = TOPK_;
#pragma unroll 1
    for (int bit = 31; bit >= 0; --bit) {
      const uint32_t want = (prefix >> bit) | 1u;
      int c = 0;
#pragma unroll
      for (int j = 0; j < PER_LANE_; ++j) c += ((keys[j] >> bit) == want) ? 1 : 0;
#pragma unroll
      for (int off = 32; off >= 1; off >>= 1) c += __shfl_xor(c, off);
      if (c >= k) prefix |= (1u << bit); else k -= c;
    }
    const int r = k;

    int gt = 0, eq = 0;
#pragma unroll
    for (int j = 0; j < PER_LANE_; ++j) {
      gt += (keys[j] > prefix) ? 1 : 0;
      eq += (keys[j] == prefix) ? 1 : 0;
    }
    uint32_t incl2 = (uint32_t)gt | ((uint32_t)eq << 16);
#pragma unroll
    for (int off = 1; off < 64; off <<= 1) {
      uint32_t y = __shfl_up(incl2, (unsigned)off);
      if (lane >= off) incl2 += y;
    }
    const int gt_base = (int)(incl2 & 0xFFFFu) - gt;
    const int eq_base = (int)(incl2 >> 16) - eq;
    int pos = gt_base + min(eq_base, r);
    int eq_seen = eq_base;
#pragma unroll
    for (int j = 0; j < PER_LANE_; ++j) {
      const uint32_t kj = keys[j];
      bool s = false;
      if (kj > prefix) s = true;
      else if (kj == prefix) { s = (eq_seen < r); eq_seen++; }
      if (s) { idx_row[pos] = (float)(base_i + j); pos++; }
    }
  }
}

// ---- kernel 3: histograms -> indicators (writes every element; no memset) ----
__global__ __launch_bounds__(256) void ptk_hist(
    const float* __restrict__ out_idx, float* __restrict__ indicators) {
  __shared__ int hist[JCHUNK_][D_];   // 64 KB

  const int tid   = threadIdx.x;
  const int b     = blockIdx.x >> 4;         // 16 chunks per b
  const int chunk = blockIdx.x & 15;
  const int j0    = chunk * JCHUNK_;

  int4* h4 = (int4*)hist;
  for (int t = tid; t < JCHUNK_ * D_ / 4; t += 256)
    h4[t] = make_int4(0, 0, 0, 0);
  __syncthreads();

  const float* __restrict__ src = out_idx + (size_t)b * NS_ * TOPK_ + j0;
  for (int t = tid; t < NS_ * 2; t += 256) {     // 2 float4 per sample (8 ranks)
    const int n = t >> 1;
    const int q = (t & 1) << 2;
    const float4 v = *reinterpret_cast<const float4*>(src + (size_t)n * TOPK_ + q);
    atomicAdd(&hist[q + 0][(int)v.x], 1);
    atomicAdd(&hist[q + 1][(int)v.y], 1);
    atomicAdd(&hist[q + 2][(int)v.z], 1);
    atomicAdd(&hist[q + 3][(int)v.w], 1);
  }
  __syncthreads();

  float4* __restrict__ dst =
      (float4*)(indicators + ((size_t)b * TOPK_ + j0) * D_);
  for (int t = tid; t < JCHUNK_ * D_ / 4; t += 256) {
    const int4 h = h4[t];
    float4 o;
    o.x = (float)h.x / (float)NS_;
    o.y = (float)h.y / (float)NS_;
    o.z = (float)h.z / (float)NS_;
    o.w = (float)h.w / (float)NS_;
    dst[t] = o;
  }
}

extern "C" void kernel_launch(void* const* d_in, const int* in_sizes, int n_in,
                              void* d_out, int out_size, void* d_ws, size_t ws_size,
                              hipStream_t stream) {
  const float* x     = (const float*)d_in[0];
  const float* noise = (const float*)d_in[1];
  float* indicators  = (float*)d_out;
  float* out_idx     = (float*)d_out + (size_t)B_ * TOPK_ * D_;
  float* cutf        = (float*)d_ws;

  hipLaunchKernelGGL(ptk_cutoff, dim3(B_), dim3(64), 0, stream, x, cutf);

  const int rows = B_ * NS_;                        // 16000
  hipLaunchKernelGGL(ptk_select, dim3(rows / WAVES_PER_BLOCK_), dim3(256), 0,
                     stream, x, noise, cutf, out_idx);

  hipLaunchKernelGGL(ptk_hist, dim3(B_ * 16), dim3(256), 0, stream,
                     out_idx, indicators);
}

// Round 7
// 232.280 us; speedup vs baseline: 1.0865x; 1.0865x over previous
//
#include <hip/hip_runtime.h>

// PerturbedTopK: x(32,2048) f32, noise(32,500,2048) f32.
// out = [indicators (32,128,2048) f32, idx (32,500,128) as f32], concatenated.
//
// R7 = R5 structure (contiguous per-lane ownership: VGPR 40, occ 55% — R6's
// interleaved layout pushed VGPR to 68 / occ to 28% and regressed) with an
// exact-quantile cutoff: kernel 1 computes the 160th-largest of x_b (slack 32
// over K=128 ~ 7 sigma of noise-induced count drift) instead of x_(128)-0.25.
// Candidates drop ~204 -> ~160. Select writes idx only; hist rebuilds
// indicators via LDS histograms (no memset, no global atomics).

constexpr int B_     = 32;
constexpr int D_     = 2048;
constexpr int NS_    = 500;
constexpr int TOPK_  = 128;
constexpr int SLACK_ = 32;               // cutoff rank = TOPK_ + SLACK_ = 160
constexpr float SIGMA_  = 0.05f;
constexpr int PER_LANE_ = D_ / 64;       // 32
constexpr int WAVES_PER_BLOCK_ = 4;
constexpr int CAP_   = 256;              // fast-path candidate cap (4 slots)
constexpr int SLOTS_ = CAP_ / 64;        // 4
constexpr int JCHUNK_ = 8;               // ranks per hist block

__device__ __forceinline__ uint32_t order_key(float f) {
  uint32_t u = __float_as_uint(f);
  return (u & 0x80000000u) ? ~u : (u | 0x80000000u);
}
__device__ __forceinline__ float inv_key(uint32_t k) {
  uint32_t u = (k & 0x80000000u) ? (k & 0x7FFFFFFFu) : ~k;
  return __uint_as_float(u);
}

// ---- kernel 1: per-b cutoff = exact (TOPK_+SLACK_)th largest of x_b ----
__global__ __launch_bounds__(64) void ptk_cutoff(const float* __restrict__ x,
                                                 float* __restrict__ cutf) {
  const int lane = threadIdx.x & 63;
  const int b = blockIdx.x;
  const float* __restrict__ xr = x + (size_t)b * D_;
  uint32_t keys[PER_LANE_];
#pragma unroll
  for (int j = 0; j < PER_LANE_; j += 4) {
    const float4 xv = *reinterpret_cast<const float4*>(xr + lane * PER_LANE_ + j);
    keys[j + 0] = order_key(xv.x); keys[j + 1] = order_key(xv.y);
    keys[j + 2] = order_key(xv.z); keys[j + 3] = order_key(xv.w);
  }
  uint32_t prefix = 0; int k = TOPK_ + SLACK_;
#pragma unroll 1
  for (int bit = 31; bit >= 0; --bit) {
    const uint32_t want = (prefix >> bit) | 1u;
    int c = 0;
#pragma unroll
    for (int j = 0; j < PER_LANE_; ++j) c += ((keys[j] >> bit) == want) ? 1 : 0;
#pragma unroll
    for (int off = 32; off >= 1; off >>= 1) c += __shfl_xor(c, off);
    if (c >= k) prefix |= (1u << bit); else k -= c;
  }
  if (lane == 0) cutf[b] = inv_key(prefix);
}

// ---- kernel 2: selection, writes idx only ----
__global__ __launch_bounds__(256) void ptk_select(
    const float* __restrict__ x, const float* __restrict__ noise,
    const float* __restrict__ cutf, float* __restrict__ out_idx) {
  __shared__ uint2 comp[WAVES_PER_BLOCK_][CAP_];

  const int lane = threadIdx.x & 63;
  const int wave = threadIdx.x >> 6;
  const int row  = blockIdx.x * WAVES_PER_BLOCK_ + wave;   // 0..15999
  const int b = row / NS_;

  const float* __restrict__ xr = x + (size_t)b * D_;
  const float* __restrict__ nr = noise + (size_t)row * D_;
  const int base_i = lane * PER_LANE_;

  float p[PER_LANE_];
#pragma unroll
  for (int j = 0; j < PER_LANE_; j += 4) {
    const float4 nv = *reinterpret_cast<const float4*>(nr + base_i + j);
    const float4 xv = *reinterpret_cast<const float4*>(xr + base_i + j);
    p[j + 0] = fmaf(SIGMA_, nv.x, xv.x);
    p[j + 1] = fmaf(SIGMA_, nv.y, xv.y);
    p[j + 2] = fmaf(SIGMA_, nv.z, xv.z);
    p[j + 3] = fmaf(SIGMA_, nv.w, xv.w);
  }

  const float cf = cutf[b];   // wave-uniform

  // candidate mask in float domain (monotone-equivalent to key >= order_key(cf))
  uint32_t m = 0;
#pragma unroll
  for (int j = 0; j < PER_LANE_; ++j) m |= (p[j] >= cf) ? (1u << j) : 0u;
  const int cnt = __popc(m);

  // ballot-based exclusive scan of cnt (6 bits) -> offset, and total C
  const uint64_t below = (lane == 0) ? 0ull : ((~0ull) >> (64 - lane));
  int offset = 0, C = 0;
#pragma unroll
  for (int t = 0; t < 6; ++t) {
    const uint64_t mb = __ballot((cnt >> t) & 1);
    offset += (int)__popcll(mb & below) << t;
    C      += (int)__popcll(mb) << t;
  }

  float* __restrict__ idx_row = out_idx + (size_t)row * TOPK_;

  if (C >= TOPK_ && C <= CAP_) {
    // ---------- fast path ----------
    {
      uint32_t mm = m; int q = offset;
      while (mm) {
        const int j = __ffs(mm) - 1; mm &= mm - 1;
        comp[wave][q] = make_uint2(order_key(p[j]), (uint32_t)(base_i + j));
        ++q;
      }
    }
    __asm__ volatile("s_waitcnt lgkmcnt(0)" ::: "memory");

    uint32_t kk[SLOTS_], ki[SLOTS_];
    bool valid[SLOTS_];
#pragma unroll
    for (int s = 0; s < SLOTS_; ++s) {
      const int q = (s << 6) + lane;
      valid[s] = (q < C);
      const uint2 v = valid[s] ? comp[wave][q] : make_uint2(0u, 0u);
      kk[s] = v.x; ki[s] = v.y;   // pad key 0 never matches a radix class
    }

    // common-prefix skip: and/or reduce over candidate keys
    uint32_t orv = 0u, andv = 0xFFFFFFFFu;
#pragma unroll
    for (int s = 0; s < SLOTS_; ++s) {
      orv  |= valid[s] ? kk[s] : 0u;
      andv &= valid[s] ? kk[s] : 0xFFFFFFFFu;
    }
#pragma unroll
    for (int off = 32; off >= 1; off >>= 1) {
      orv  |= __shfl_xor(orv, off);
      andv &= __shfl_xor(andv, off);
    }
    const uint32_t diff = orv ^ andv;

    uint32_t prefix; int r;
    if (diff == 0u) {
      // all candidate keys identical (degenerate): kth is that key
      prefix = orv; r = TOPK_;
    } else {
      const int startbit = 31 - __clz(diff);
      prefix = (startbit == 31) ? 0u : (andv & (0xFFFFFFFFu << (startbit + 1)));
      int k = TOPK_;
      int A = C;   // keys matching prefix in bits above current
#pragma unroll 1
      for (int bit = startbit; bit >= 0; --bit) {
        const uint32_t want = (prefix >> bit) | 1u;
        int c = 0;
#pragma unroll
        for (int s = 0; s < SLOTS_; ++s)
          c += __popcll(__ballot((kk[s] >> bit) == want));
        if (c >= k) { prefix |= (1u << bit); A = c; }
        else        { k -= c; A -= c; }
        if (A == 1) {
          // unique survivor: it IS the kth-largest (k==1). broadcast its key.
          uint32_t mykey = 0u; bool have = false;
#pragma unroll
          for (int s = 0; s < SLOTS_; ++s) {
            const bool hit = valid[s] && ((kk[s] >> bit) == (prefix >> bit));
            mykey = hit ? kk[s] : mykey;
            have |= hit;
          }
          const uint64_t mb = __ballot(have);
          const int src = __ffsll((unsigned long long)mb) - 1;
          prefix = __shfl(mykey, src);
          k = 1;
          break;
        }
      }
      r = k;
    }

    // ballot-ranked emission, ascending index order
    int sel_run = 0, eq_run = 0;
#pragma unroll
    for (int s = 0; s < SLOTS_; ++s) {
      const bool gt = kk[s] > prefix;
      const bool eq = kk[s] == prefix;
      const uint64_t meq = __ballot(eq);
      const int eqrank = eq_run + __popcll(meq & below);
      const bool sel = gt || (eq && (eqrank < r));
      const uint64_t msel = __ballot(sel);
      if (sel) {
        const int pos = sel_run + __popcll(msel & below);
        idx_row[pos] = (float)(int)ki[s];
      }
      sel_run += __popcll(msel);
      eq_run  += __popcll(meq);
    }
  } else {
    // ---------- fallback (rare): exact select over all 2048 ----------
    uint32_t keys[PER_LANE_];
#pragma unroll
    for (int j = 0; j < PER_LANE_; ++j) keys[j] = order_key(p[j]);

    uint32_t prefix = 0; int k = TOPK_;
#pragma unroll 1
    for (int bit = 31; bit >= 0; --bit) {
      const uint32_t want = (prefix >> bit) | 1u;
      int c = 0;
#pragma unroll
      for (int j = 0; j < PER_LANE_; ++j) c += ((keys[j] >> bit) == want) ? 1 : 0;
#pragma unroll
      for (int off = 32; off >= 1; off >>= 1) c += __shfl_xor(c, off);
      if (c >= k) prefix |= (1u << bit); else k -= c;
    }
    const int r = k;

    int gt = 0, eq = 0;
#pragma unroll
    for (int j = 0; j < PER_LANE_; ++j) {
      gt += (keys[j] > prefix) ? 1 : 0;
      eq += (keys[j] == prefix) ? 1 : 0;
    }
    uint32_t incl2 = (uint32_t)gt | ((uint32_t)eq << 16);
#pragma unroll
    for (int off = 1; off < 64; off <<= 1) {
      uint32_t y = __shfl_up(incl2, (unsigned)off);
      if (lane >= off) incl2 += y;
    }
    const int gt_base = (int)(incl2 & 0xFFFFu) - gt;
    const int eq_base = (int)(incl2 >> 16) - eq;
    int pos = gt_base + min(eq_base, r);
    int eq_seen = eq_base;
#pragma unroll
    for (int j = 0; j < PER_LANE_; ++j) {
      const uint32_t kj = keys[j];
      bool s = false;
      if (kj > prefix) s = true;
      else if (kj == prefix) { s = (eq_seen < r); eq_seen++; }
      if (s) { idx_row[pos] = (float)(base_i + j); pos++; }
    }
  }
}

// ---- kernel 3: histograms -> indicators (writes every element; no memset) ----
__global__ __launch_bounds__(256) void ptk_hist(
    const float* __restrict__ out_idx, float* __restrict__ indicators) {
  __shared__ int hist[JCHUNK_][D_];   // 64 KB

  const int tid   = threadIdx.x;
  const int b     = blockIdx.x >> 4;         // 16 chunks per b
  const int chunk = blockIdx.x & 15;
  const int j0    = chunk * JCHUNK_;

  int4* h4 = (int4*)hist;
  for (int t = tid; t < JCHUNK_ * D_ / 4; t += 256)
    h4[t] = make_int4(0, 0, 0, 0);
  __syncthreads();

  const float* __restrict__ src = out_idx + (size_t)b * NS_ * TOPK_ + j0;
  for (int t = tid; t < NS_ * 2; t += 256) {     // 2 float4 per sample (8 ranks)
    const int n = t >> 1;
    const int q = (t & 1) << 2;
    const float4 v = *reinterpret_cast<const float4*>(src + (size_t)n * TOPK_ + q);
    atomicAdd(&hist[q + 0][(int)v.x], 1);
    atomicAdd(&hist[q + 1][(int)v.y], 1);
    atomicAdd(&hist[q + 2][(int)v.z], 1);
    atomicAdd(&hist[q + 3][(int)v.w], 1);
  }
  __syncthreads();

  float4* __restrict__ dst =
      (float4*)(indicators + ((size_t)b * TOPK_ + j0) * D_);
  for (int t = tid; t < JCHUNK_ * D_ / 4; t += 256) {
    const int4 h = h4[t];
    float4 o;
    o.x = (float)h.x / (float)NS_;
    o.y = (float)h.y / (float)NS_;
    o.z = (float)h.z / (float)NS_;
    o.w = (float)h.w / (float)NS_;
    dst[t] = o;
  }
}

extern "C" void kernel_launch(void* const* d_in, const int* in_sizes, int n_in,
                              void* d_out, int out_size, void* d_ws, size_t ws_size,
                              hipStream_t stream) {
  const float* x     = (const float*)d_in[0];
  const float* noise = (const float*)d_in[1];
  float* indicators  = (float*)d_out;
  float* out_idx     = (float*)d_out + (size_t)B_ * TOPK_ * D_;
  float* cutf        = (float*)d_ws;

  hipLaunchKernelGGL(ptk_cutoff, dim3(B_), dim3(64), 0, stream, x, cutf);

  const int rows = B_ * NS_;                        // 16000
  hipLaunchKernelGGL(ptk_select, dim3(rows / WAVES_PER_BLOCK_), dim3(256), 0,
                     stream, x, noise, cutf, out_idx);

  hipLaunchKernelGGL(ptk_hist, dim3(B_ * 16), dim3(256), 0, stream,
                     out_idx, indicators);
}

// Round 8
// 224.108 us; speedup vs baseline: 1.1261x; 1.0365x over previous
//
#include <hip/hip_runtime.h>

// PerturbedTopK: x(32,2048) f32, noise(32,500,2048) f32.
// out = [indicators (32,128,2048) f32, idx (32,500,128) as f32], concatenated.
//
// R8: 2 waves per row in select (1024 elems / 16 per lane each) -> 32000
// waves for latency hiding; halves per-wave VGPR+load footprint. Each half
// compacts candidates (>= per-b 160th-quantile cutoff) into its own LDS
// region; after one barrier the even wave stitches both regions (ascending
// index order preserved) and runs the R5/R7 ballot radix select + emission;
// odd wave retires. Fallback (C outside [128,256], ~7sigma): even wave
// reloads the full row and runs the verified R1 path. Hist/cutoff from R7.

constexpr int B_     = 32;
constexpr int D_     = 2048;
constexpr int NS_    = 500;
constexpr int TOPK_  = 128;
constexpr int SLACK_ = 32;               // cutoff rank = 160
constexpr float SIGMA_  = 0.05f;
constexpr int PER_LANE_ = D_ / 64;       // 32 (fallback/cutoff)
constexpr int HALF_  = D_ / 2;           // 1024
constexpr int HPL_   = HALF_ / 64;       // 16 elements per lane per half-row
constexpr int CAP_   = 256;              // fast-path candidate cap (4 slots)
constexpr int SLOTS_ = CAP_ / 64;        // 4
constexpr int JCHUNK_ = 8;               // ranks per hist block

__device__ __forceinline__ uint32_t order_key(float f) {
  uint32_t u = __float_as_uint(f);
  return (u & 0x80000000u) ? ~u : (u | 0x80000000u);
}
__device__ __forceinline__ float inv_key(uint32_t k) {
  uint32_t u = (k & 0x80000000u) ? (k & 0x7FFFFFFFu) : ~k;
  return __uint_as_float(u);
}

// ---- kernel 1: per-b cutoff = exact (TOPK_+SLACK_)th largest of x_b ----
__global__ __launch_bounds__(64) void ptk_cutoff(const float* __restrict__ x,
                                                 float* __restrict__ cutf) {
  const int lane = threadIdx.x & 63;
  const int b = blockIdx.x;
  const float* __restrict__ xr = x + (size_t)b * D_;
  uint32_t keys[PER_LANE_];
#pragma unroll
  for (int j = 0; j < PER_LANE_; j += 4) {
    const float4 xv = *reinterpret_cast<const float4*>(xr + lane * PER_LANE_ + j);
    keys[j + 0] = order_key(xv.x); keys[j + 1] = order_key(xv.y);
    keys[j + 2] = order_key(xv.z); keys[j + 3] = order_key(xv.w);
  }
  uint32_t prefix = 0; int k = TOPK_ + SLACK_;
#pragma unroll 1
  for (int bit = 31; bit >= 0; --bit) {
    const uint32_t want = (prefix >> bit) | 1u;
    int c = 0;
#pragma unroll
    for (int j = 0; j < PER_LANE_; ++j) c += ((keys[j] >> bit) == want) ? 1 : 0;
#pragma unroll
    for (int off = 32; off >= 1; off >>= 1) c += __shfl_xor(c, off);
    if (c >= k) prefix |= (1u << bit); else k -= c;
  }
  if (lane == 0) cutf[b] = inv_key(prefix);
}

// ---- kernel 2: selection, 2 waves per row, writes idx only ----
__global__ __launch_bounds__(256) void ptk_select(
    const float* __restrict__ x, const float* __restrict__ noise,
    const float* __restrict__ cutf, float* __restrict__ out_idx) {
  // two row-pairs per 256-thread block; per pair: two 256-entry regions
  __shared__ uint2 comp[2][2 * CAP_];
  __shared__ int cnts[2][2];

  const int lane = threadIdx.x & 63;
  const int wave = threadIdx.x >> 6;
  const int pair = wave >> 1;            // 0..1  (row within block)
  const int half = wave & 1;             // 0..1  (half of the row)
  const int row  = blockIdx.x * 2 + pair;  // 0..15999
  const int b = row / NS_;

  const float* __restrict__ xr = x + (size_t)b * D_ + half * HALF_;
  const float* __restrict__ nr = noise + (size_t)row * D_ + half * HALF_;
  const int base_l = lane * HPL_;          // within half
  const int base_i = half * HALF_ + base_l;

  float p[HPL_];
#pragma unroll
  for (int j = 0; j < HPL_; j += 4) {
    const float4 nv = *reinterpret_cast<const float4*>(nr + base_l + j);
    const float4 xv = *reinterpret_cast<const float4*>(xr + base_l + j);
    p[j + 0] = fmaf(SIGMA_, nv.x, xv.x);
    p[j + 1] = fmaf(SIGMA_, nv.y, xv.y);
    p[j + 2] = fmaf(SIGMA_, nv.z, xv.z);
    p[j + 3] = fmaf(SIGMA_, nv.w, xv.w);
  }

  const float cf = cutf[b];   // wave-uniform

  uint32_t m = 0;
#pragma unroll
  for (int j = 0; j < HPL_; ++j) m |= (p[j] >= cf) ? (1u << j) : 0u;
  const int cnt = __popc(m);

  // ballot-based exclusive scan of cnt (5 bits, cnt<=16) -> offset, total Cw
  const uint64_t below = (lane == 0) ? 0ull : ((~0ull) >> (64 - lane));
  int offset = 0, Cw = 0;
#pragma unroll
  for (int t = 0; t < 5; ++t) {
    const uint64_t mb = __ballot((cnt >> t) & 1);
    offset += (int)__popcll(mb & below) << t;
    Cw     += (int)__popcll(mb) << t;
  }
  if (lane == 0) cnts[pair][half] = Cw;

  // compact this half's candidates (ascending index) into its region
  {
    uint32_t mm = m; int q = half * CAP_ + offset;
    while (mm) {
      const int j = __ffs(mm) - 1; mm &= mm - 1;
      comp[pair][q] = make_uint2(order_key(p[j]), (uint32_t)(base_i + j));
      ++q;
    }
  }
  __syncthreads();

  if (half) return;   // odd waves retire; even wave finishes the row

  const int C0 = cnts[pair][0];
  const int C1 = cnts[pair][1];
  const int C  = C0 + C1;

  float* __restrict__ idx_row = out_idx + (size_t)row * TOPK_;

  if (C >= TOPK_ && C <= CAP_) {
    // ---------- fast path: stitch regions (region0 = lower indices) ----------
    uint32_t kk[SLOTS_], ki[SLOTS_];
    bool valid[SLOTS_];
#pragma unroll
    for (int s = 0; s < SLOTS_; ++s) {
      const int q = (s << 6) + lane;
      const int a = (q < C0) ? q : (CAP_ + q - C0);
      valid[s] = (q < C);
      const uint2 v = valid[s] ? comp[pair][a] : make_uint2(0u, 0u);
      kk[s] = v.x; ki[s] = v.y;   // pad key 0 never matches a radix class
    }

    // common-prefix skip: and/or reduce over candidate keys
    uint32_t orv = 0u, andv = 0xFFFFFFFFu;
#pragma unroll
    for (int s = 0; s < SLOTS_; ++s) {
      orv  |= valid[s] ? kk[s] : 0u;
      andv &= valid[s] ? kk[s] : 0xFFFFFFFFu;
    }
#pragma unroll
    for (int off = 32; off >= 1; off >>= 1) {
      orv  |= __shfl_xor(orv, off);
      andv &= __shfl_xor(andv, off);
    }
    const uint32_t diff = orv ^ andv;

    uint32_t prefix; int r;
    if (diff == 0u) {
      prefix = orv; r = TOPK_;
    } else {
      const int startbit = 31 - __clz(diff);
      prefix = (startbit == 31) ? 0u : (andv & (0xFFFFFFFFu << (startbit + 1)));
      int k = TOPK_;
      int A = C;
#pragma unroll 1
      for (int bit = startbit; bit >= 0; --bit) {
        const uint32_t want = (prefix >> bit) | 1u;
        int c = 0;
#pragma unroll
        for (int s = 0; s < SLOTS_; ++s)
          c += __popcll(__ballot((kk[s] >> bit) == want));
        if (c >= k) { prefix |= (1u << bit); A = c; }
        else        { k -= c; A -= c; }
        if (A == 1) {
          uint32_t mykey = 0u; bool have = false;
#pragma unroll
          for (int s = 0; s < SLOTS_; ++s) {
            const bool hit = valid[s] && ((kk[s] >> bit) == (prefix >> bit));
            mykey = hit ? kk[s] : mykey;
            have |= hit;
          }
          const uint64_t mb = __ballot(have);
          const int src = __ffsll((unsigned long long)mb) - 1;
          prefix = __shfl(mykey, src);
          k = 1;
          break;
        }
      }
      r = k;
    }

    // ballot-ranked emission, ascending index order
    int sel_run = 0, eq_run = 0;
#pragma unroll
    for (int s = 0; s < SLOTS_; ++s) {
      const bool gt = kk[s] > prefix;
      const bool eq = kk[s] == prefix;
      const uint64_t meq = __ballot(eq);
      const int eqrank = eq_run + __popcll(meq & below);
      const bool sel = gt || (eq && (eqrank < r));
      const uint64_t msel = __ballot(sel);
      if (sel) {
        const int pos = sel_run + __popcll(msel & below);
        idx_row[pos] = (float)(int)ki[s];
      }
      sel_run += __popcll(msel);
      eq_run  += __popcll(meq);
    }
  } else {
    // ---------- fallback (rare): even wave reloads full row, R1 exact ----------
    const float* __restrict__ xr2 = x + (size_t)b * D_;
    const float* __restrict__ nr2 = noise + (size_t)row * D_;
    const int bi = lane * PER_LANE_;
    uint32_t keys[PER_LANE_];
#pragma unroll
    for (int j = 0; j < PER_LANE_; ++j)
      keys[j] = order_key(fmaf(SIGMA_, nr2[bi + j], xr2[bi + j]));

    uint32_t prefix = 0; int k = TOPK_;
#pragma unroll 1
    for (int bit = 31; bit >= 0; --bit) {
      const uint32_t want = (prefix >> bit) | 1u;
      int c = 0;
#pragma unroll
      for (int j = 0; j < PER_LANE_; ++j) c += ((keys[j] >> bit) == want) ? 1 : 0;
#pragma unroll
      for (int off = 32; off >= 1; off >>= 1) c += __shfl_xor(c, off);
      if (c >= k) prefix |= (1u << bit); else k -= c;
    }
    const int r = k;

    int gt = 0, eq = 0;
#pragma unroll
    for (int j = 0; j < PER_LANE_; ++j) {
      gt += (keys[j] > prefix) ? 1 : 0;
      eq += (keys[j] == prefix) ? 1 : 0;
    }
    uint32_t incl2 = (uint32_t)gt | ((uint32_t)eq << 16);
#pragma unroll
    for (int off = 1; off < 64; off <<= 1) {
      uint32_t y = __shfl_up(incl2, (unsigned)off);
      if (lane >= off) incl2 += y;
    }
    const int gt_base = (int)(incl2 & 0xFFFFu) - gt;
    const int eq_base = (int)(incl2 >> 16) - eq;
    int pos = gt_base + min(eq_base, r);
    int eq_seen = eq_base;
#pragma unroll
    for (int j = 0; j < PER_LANE_; ++j) {
      const uint32_t kj = keys[j];
      bool s = false;
      if (kj > prefix) s = true;
      else if (kj == prefix) { s = (eq_seen < r); eq_seen++; }
      if (s) { idx_row[pos] = (float)(bi + j); pos++; }
    }
  }
}

// ---- kernel 3: histograms -> indicators (writes every element; no memset) ----
__global__ __launch_bounds__(256) void ptk_hist(
    const float* __restrict__ out_idx, float* __restrict__ indicators) {
  __shared__ int hist[JCHUNK_][D_];   // 64 KB

  const int tid   = threadIdx.x;
  const int b     = blockIdx.x >> 4;         // 16 chunks per b
  const int chunk = blockIdx.x & 15;
  const int j0    = chunk * JCHUNK_;

  int4* h4 = (int4*)hist;
  for (int t = tid; t < JCHUNK_ * D_ / 4; t += 256)
    h4[t] = make_int4(0, 0, 0, 0);
  __syncthreads();

  const float* __restrict__ src = out_idx + (size_t)b * NS_ * TOPK_ + j0;
  for (int t = tid; t < NS_ * 2; t += 256) {     // 2 float4 per sample (8 ranks)
    const int n = t >> 1;
    const int q = (t & 1) << 2;
    const float4 v = *reinterpret_cast<const float4*>(src + (size_t)n * TOPK_ + q);
    atomicAdd(&hist[q + 0][(int)v.x], 1);
    atomicAdd(&hist[q + 1][(int)v.y], 1);
    atomicAdd(&hist[q + 2][(int)v.z], 1);
    atomicAdd(&hist[q + 3][(int)v.w], 1);
  }
  __syncthreads();

  float4* __restrict__ dst =
      (float4*)(indicators + ((size_t)b * TOPK_ + j0) * D_);
  for (int t = tid; t < JCHUNK_ * D_ / 4; t += 256) {
    const int4 h = h4[t];
    float4 o;
    o.x = (float)h.x / (float)NS_;
    o.y = (float)h.y / (float)NS_;
    o.z = (float)h.z / (float)NS_;
    o.w = (float)h.w / (float)NS_;
    dst[t] = o;
  }
}

extern "C" void kernel_launch(void* const* d_in, const int* in_sizes, int n_in,
                              void* d_out, int out_size, void* d_ws, size_t ws_size,
                              hipStream_t stream) {
  const float* x     = (const float*)d_in[0];
  const float* noise = (const float*)d_in[1];
  float* indicators  = (float*)d_out;
  float* out_idx     = (float*)d_out + (size_t)B_ * TOPK_ * D_;
  float* cutf        = (float*)d_ws;

  hipLaunchKernelGGL(ptk_cutoff, dim3(B_), dim3(64), 0, stream, x, cutf);

  const int rows = B_ * NS_;                        // 16000
  hipLaunchKernelGGL(ptk_select, dim3(rows / 2), dim3(256), 0, stream,
                     x, noise, cutf, out_idx);

  hipLaunchKernelGGL(ptk_hist, dim3(B_ * 16), dim3(256), 0, stream,
                     out_idx, indicators);
}